// Round 5
// baseline (153.776 us; speedup 1.0000x reference)
//
#include <hip/hip_runtime.h>
#include <hip/hip_bf16.h>

#define FIN 128
#define FOUT 64
#define TILE_ROWS 64       // rows per gemm block = 4 waves x 16

#define EPB 8192           // edges per scatter chunk (runs of ~10.5/bucket)
#define NPB 64             // nodes per bucket (d >> 6)
#define NBUK_MAX 800
#define CAP 1408           // fixed records region per bucket (mean 1024, +12 sigma)

// Workspace layout (bytes), ws >= 268 MB:
//   [0, 6,400,000)         support : N*64 bf16
//   OFF_CUR   +3,200       cur     : NBUK int (bucket fill counters)
//   OFF_OVFC  +64          ovfc    : 1 int   (overflow count)
//   OFF_TMP   +9,011,200   tmp     : NBUK_MAX*CAP int2, fixed-stride regions
//   OFF_OVF   +12,800,000  ovf     : E int4 {recx, recy, bucket, pad}
#define OFF_CUR   6400000
#define OFF_OVFC  6403200
#define OFF_TMP   6403264
#define OFF_OVF   15414464

typedef short bf16x8 __attribute__((ext_vector_type(8)));
typedef float f32x4  __attribute__((ext_vector_type(4)));

__device__ inline ushort f32_to_bf16_rne(float f) {
    unsigned u = __float_as_uint(f);
    u += 0x7FFFu + ((u >> 16) & 1u);
    return (ushort)(u >> 16);
}
__device__ inline float bf16_to_f32(ushort h) {
    return __uint_as_float((unsigned)h << 16);
}

// ---------------------------------------------------------------------------
// Fused, independent branches (no intra-kernel ordering, no fences):
//   blocks [0,GB):       MFMA gemm (W staged to LDS bf16, transposed+swizzled)
//   blocks [GB,GB+SBP):  scatter chunk -> fixed-CAP bucket regions in tmp.
// Scatter: LDS hist of the chunk -> ONE returning global atomicAdd per
// present bucket (range reservation) -> place via LDS cursors.
// rec = {src | (d&63)<<16, ev_bits}   (src < 65536: N = 50000 ok)
// ---------------------------------------------------------------------------
union __align__(16) K1Sh {
    ushort wt[FOUT * FIN];                       // 16 KB (gemm: WT[n][k] swz)
    struct { int h[NBUK_MAX]; int c[NBUK_MAX]; } sc;  // 6.4 KB (scatter)
};

__global__ __launch_bounds__(256) void gemm_scatter_kernel(
    const float* __restrict__ x, const float* __restrict__ t,
    const float* __restrict__ W, ushort* __restrict__ support, int N,
    const int* __restrict__ src, const int* __restrict__ dst,
    const float* __restrict__ ev, int* __restrict__ cur,
    int2* __restrict__ tmp, int* __restrict__ ovfc, int4* __restrict__ ovf,
    int E, int SBP, int NBUK, int GB)
{
    __shared__ K1Sh sh;
    const int tid = threadIdx.x;

    if (blockIdx.x >= (unsigned)GB) {
        // ---- scatter branch ----
        const int chunk = blockIdx.x - GB;
        const int e0    = chunk * EPB;

        for (int i = tid; i < NBUK; i += 256) sh.sc.h[i] = 0;
        __syncthreads();

        // pass 1: local bucket counts
        for (int i = tid; i < EPB; i += 256) {
            int e = e0 + i;
            if (e < E) atomicAdd(&sh.sc.h[dst[e] >> 6], 1);
        }
        __syncthreads();

        // pass 2: reserve a contiguous slice of each present bucket's region
        for (int j = tid; j < NBUK; j += 256) {
            int hj = sh.sc.h[j];
            if (hj) sh.sc.c[j] = atomicAdd(&cur[j], hj);
        }
        __syncthreads();

        // pass 3: place (dst re-read is L2-hot)
        for (int i = tid; i < EPB; i += 256) {
            int e = e0 + i;
            if (e < E) {
                int d = dst[e];
                int j = d >> 6;
                int s = atomicAdd(&sh.sc.c[j], 1);
                int2 rec = make_int2(src[e] | ((d & (NPB - 1)) << 16),
                                     __float_as_int(ev[e]));
                if (s < CAP) {
                    tmp[(size_t)j * CAP + s] = rec;
                } else {                 // never at this size; kept correct
                    int o = atomicAdd(ovfc, 1);
                    if (o < E) ovf[o] = make_int4(rec.x, rec.y, j, 0);
                }
            }
        }
        return;
    }

    // ---- MFMA gemm branch ----
    const int gb   = blockIdx.x;
    const int lane = tid & 63;
    const int w    = tid >> 6;          // wave 0..3
    const int ln   = lane & 15;
    const int q    = lane >> 4;         // quad 0..3
    const int rowb = gb * TILE_ROWS + w * 16;
    const int arow = rowb + ln;

    // Stage W -> LDS bf16, transposed WT[n][k]; 16B slot XOR-swizzled by n&7.
    for (int idx = tid; idx < FIN * FOUT; idx += 256) {
        int k = idx >> 6;          // 0..127   (idx = k*FOUT + n)
        int n = idx & 63;          // 0..63
        sh.wt[n * FIN + (k ^ ((n & 7) << 3))] = f32_to_bf16_rne(W[idx]);
    }
    __syncthreads();

    f32x4 acc[4];
    #pragma unroll
    for (int nt = 0; nt < 4; ++nt)
        #pragma unroll
        for (int r = 0; r < 4; ++r) acc[nt][r] = 0.f;

    const bool aok = (arow < N);
    const float* xrow = &x[(size_t)arow * FIN];

    #pragma unroll
    for (int kc = 0; kc < 4; ++kc) {
        float xs[8];
        #pragma unroll
        for (int j = 0; j < 8; ++j) xs[j] = 0.f;
        if (aok) {
            float4 x0 = *(const float4*)&xrow[kc * 32 + q * 8];
            float4 x1 = *(const float4*)&xrow[kc * 32 + q * 8 + 4];
            xs[0] = x0.x; xs[1] = x0.y; xs[2] = x0.z; xs[3] = x0.w;
            xs[4] = x1.x; xs[5] = x1.y; xs[6] = x1.z; xs[7] = x1.w;
        }
        bf16x8 a;
        #pragma unroll
        for (int j = 0; j < 8; ++j) a[j] = (short)f32_to_bf16_rne(xs[j]);

        const int k0 = kc * 32 + q * 8;
        #pragma unroll
        for (int nt = 0; nt < 4; ++nt) {
            bf16x8 b = *(const bf16x8*)
                &sh.wt[(nt * 16 + ln) * FIN + (k0 ^ ((ln & 7) << 3))];
            acc[nt] = __builtin_amdgcn_mfma_f32_16x16x32_bf16(a, b, acc[nt], 0, 0, 0);
        }
    }

    // epilogue: D[m=q*4+reg][n=ln]; scale by t[row]; store bf16
    #pragma unroll
    for (int reg = 0; reg < 4; ++reg) {
        int r = rowb + q * 4 + reg;
        if (r < N) {
            float tv = t[r];
            #pragma unroll
            for (int nt = 0; nt < 4; ++nt)
                support[(size_t)r * FOUT + nt * 16 + ln] =
                    f32_to_bf16_rne(acc[nt][reg] * tv);
        }
    }
}

// ---------------------------------------------------------------------------
// bucket_gather: one block per 64-node bucket. Region [B*CAP, B*CAP+placed)
// read once into LDS; count -> wave-0 shfl scan -> reorder -> walk v2:
// per node, 4 records in flight (wave split into 4 groups of 16 lanes;
// each lane covers 4 features via one 8B uint2 load), cross-group
// shfl_xor reduction, coalesced float4 store. Zero-count nodes fall out
// naturally (empty loop -> bias row). No float atomics in normal path.
// ---------------------------------------------------------------------------
__global__ __launch_bounds__(256) void bucket_gather_kernel(
    const int* __restrict__ curg, const int2* __restrict__ tmp,
    const ushort* __restrict__ support, const float* __restrict__ bias,
    float* __restrict__ out, const int* __restrict__ ovfc,
    const int4* __restrict__ ovf, int E, int N, int NBUK)
{
    __shared__ int2 raw[CAP];           // 11 KB
    __shared__ int2 sorted[CAP];        // 11 KB
    __shared__ int  cnt[NPB];
    __shared__ int  starts[NPB + 1];
    __shared__ int  cur[NPB];
    __shared__ int  novs;

    const int tid   = threadIdx.x;
    const int w     = tid >> 6;
    const int lane  = tid & 63;
    const int B     = blockIdx.x;
    const int node0 = B * NPB;

    const int base   = B * CAP;
    const int tot    = curg[B];
    const int placed = (tot < CAP) ? tot : CAP;

    if (tid < NPB) cnt[tid] = 0;
    __syncthreads();

    // single global read of tmp region: stage + count
    for (int i = tid; i < placed; i += 256) {
        int2 r = tmp[base + i];
        raw[i] = r;
        atomicAdd(&cnt[(r.x >> 16) & (NPB - 1)], 1);
    }
    __syncthreads();

    // wave-0 shfl scan over 64 counters
    if (tid < 64) {
        int v   = cnt[tid];
        int val = v;
        #pragma unroll
        for (int d = 1; d < NPB; d <<= 1) {
            int n = __shfl_up(val, d);
            if (tid >= d) val += n;
        }
        starts[tid] = val - v;
        cur[tid]    = val - v;
        if (tid == 0) starts[NPB] = placed;
    }
    __syncthreads();

    // reorder LDS -> LDS
    for (int i = tid; i < placed; i += 256) {
        int2 r  = raw[i];
        int pos = atomicAdd(&cur[(r.x >> 16) & (NPB - 1)], 1);
        sorted[pos] = r;
    }
    __syncthreads();

    // ---- walk v2: wave w owns nodes [w*16, (w+1)*16) ----
    const int fl = lane & 15;           // feature block 0..15 (4 feats each)
    const int g  = lane >> 4;           // record group 0..3
    const float4 bv4 = *(const float4*)&bias[fl * 4];

    for (int nn = 0; nn < 16; ++nn) {
        const int nl = w * 16 + nn;     // node-local index 0..63
        const int rb = starts[nl];
        const int re = starts[nl + 1];

        float a0 = 0.f, a1 = 0.f, a2 = 0.f, a3 = 0.f;
        for (int i = rb + g; i < re; i += 4) {
            int2 r = sorted[i];                           // broadcast in group
            uint2 u = *(const uint2*)
                &support[(size_t)(r.x & 0xFFFF) * FOUT + fl * 4];
            float wg = __int_as_float(r.y);
            a0 += bf16_to_f32((ushort)(u.x & 0xFFFFu)) * wg;
            a1 += bf16_to_f32((ushort)(u.x >> 16)) * wg;
            a2 += bf16_to_f32((ushort)(u.y & 0xFFFFu)) * wg;
            a3 += bf16_to_f32((ushort)(u.y >> 16)) * wg;
        }
        // reduce across the 4 groups (lanes fl, fl+16, fl+32, fl+48)
        #pragma unroll
        for (int d = 16; d < 64; d <<= 1) {
            a0 += __shfl_xor(a0, d);
            a1 += __shfl_xor(a1, d);
            a2 += __shfl_xor(a2, d);
            a3 += __shfl_xor(a3, d);
        }
        const int node = node0 + nl;
        if (g == 0 && node < N) {
            float4 o;
            o.x = a0 + bv4.x; o.y = a1 + bv4.y;
            o.z = a2 + bv4.z; o.w = a3 + bv4.w;
            *(float4*)&out[(size_t)node * FOUT + fl * 4] = o;
        }
    }

    // overflow tail: never taken at this size; kept for correctness.
    // Owning block applies its bucket's overflow via atomicAdd AFTER its own
    // plain stores; guarded __threadfence makes those stores visible to the
    // RMWs (fence executes only when overflow actually occurred).
    __syncthreads();
    if (tid == 0) novs = *ovfc;
    __syncthreads();
    int nov = novs;
    if (nov > 0) {
        if (nov > E) nov = E;
        __threadfence();
        for (int k = w; k < nov; k += 4) {
            int4 r = ovf[k];
            if (r.z == B) {
                int node = node0 + ((r.x >> 16) & (NPB - 1));
                if (node < N) {
                    float v = bf16_to_f32(
                        support[(size_t)(r.x & 0xFFFF) * FOUT + lane]);
                    atomicAdd(&out[(size_t)node * FOUT + lane],
                              v * __int_as_float(r.y));
                }
            }
        }
    }
}

extern "C" void kernel_launch(void* const* d_in, const int* in_sizes, int n_in,
                              void* d_out, int out_size, void* d_ws, size_t ws_size,
                              hipStream_t stream) {
    const float* x    = (const float*)d_in[0];
    const float* t    = (const float*)d_in[1];
    const int*   src  = (const int*)d_in[2];
    const int*   dst  = (const int*)d_in[3];
    const float* ev   = (const float*)d_in[4];
    const float* W    = (const float*)d_in[5];
    const float* bias = (const float*)d_in[6];
    float* out = (float*)d_out;

    const int N = in_sizes[1];   // 50000
    const int E = in_sizes[2];   // 800000

    char*   ws      = (char*)d_ws;
    ushort* support = (ushort*)ws;
    int*    cur     = (int*)(ws + OFF_CUR);
    int*    ovfc    = (int*)(ws + OFF_OVFC);
    int2*   tmp     = (int2*)(ws + OFF_TMP);
    int4*   ovf     = (int4*)(ws + OFF_OVF);

    const int GB   = (N + TILE_ROWS - 1) / TILE_ROWS;       // 782
    const int SBP  = (E + EPB - 1) / EPB;                   // 98
    const int NBUK = (N + NPB - 1) / NPB;                   // 782

    // zero bucket cursors + overflow count (3.3 KB, graph-capturable)
    hipMemsetAsync(ws + OFF_CUR, 0, OFF_TMP - OFF_CUR, stream);

    // 1) fused independent branches: MFMA gemm || fixed-CAP scatter
    gemm_scatter_kernel<<<GB + SBP, 256, 0, stream>>>(
        x, t, W, support, N, src, dst, ev, cur, tmp, ovfc, ovf,
        E, SBP, NBUK, GB);

    // 2) per-bucket LDS sort + 4-wide record walk -> out (+bias)
    bucket_gather_kernel<<<NBUK, 256, 0, stream>>>(
        cur, tmp, support, bias, out, ovfc, ovf, E, N, NBUK);
}

// Round 6
// 152.416 us; speedup vs baseline: 1.0089x; 1.0089x over previous
//
#include <hip/hip_runtime.h>
#include <hip/hip_bf16.h>

#define FIN 128
#define FOUT 64
#define TILE_ROWS 64       // rows per gemm block = 4 waves x 16

#define EPB 2048           // edges per scatter chunk (391 blocks -> short tail)
#define CAPN 64            // fixed record slots per node (mean deg 16; P(>64)~1e-17)

// Workspace layout (bytes), ws >= 268 MB:
//   [0, 6,400,000)         support : N*64 bf16
//   OFF_CUR   +200,000     cur     : N int (per-node fill counters)
//   OFF_OVFC  +64          ovfc    : 1 int (overflow count)
//   OFF_TMP   +25,600,000  tmp     : N*CAPN int2 rows {src, ev_bits}
//   OFF_OVF   +12,800,000  ovf     : E int4 {src, ev_bits, node, pad}
#define OFF_CUR   6400000
#define OFF_OVFC  6600000
#define OFF_TMP   6600064
#define OFF_OVF   32200064

typedef short bf16x8 __attribute__((ext_vector_type(8)));
typedef float f32x4  __attribute__((ext_vector_type(4)));

__device__ inline ushort f32_to_bf16_rne(float f) {
    unsigned u = __float_as_uint(f);
    u += 0x7FFFu + ((u >> 16) & 1u);
    return (ushort)(u >> 16);
}
__device__ inline float bf16_to_f32(ushort h) {
    return __uint_as_float((unsigned)h << 16);
}

// ---------------------------------------------------------------------------
// Fused, independent branches:
//   blocks [0,GB):       MFMA gemm (W staged to LDS bf16, transposed+swizzled)
//   blocks [GB,GB+SBP):  direct scatter -> per-node fixed rows in tmp.
// Scatter is ONE streaming pass: coalesced src/dst/ev reads, one returning
// device-scope atomicAdd on cur[dst], one 8B store. No LDS, no hist, no
// reservation pass (bucket == node, rows are pre-sized).
// ---------------------------------------------------------------------------
union __align__(16) K1Sh {
    ushort wt[FOUT * FIN];     // 16 KB (gemm: WT[n][k] swizzled)
};

__global__ __launch_bounds__(256) void gemm_scatter_kernel(
    const float* __restrict__ x, const float* __restrict__ t,
    const float* __restrict__ W, ushort* __restrict__ support, int N,
    const int* __restrict__ src, const int* __restrict__ dst,
    const float* __restrict__ ev, int* __restrict__ cur,
    int2* __restrict__ tmp, int* __restrict__ ovfc, int4* __restrict__ ovf,
    int E, int SBP, int GB)
{
    __shared__ K1Sh sh;
    const int tid = threadIdx.x;

    if (blockIdx.x >= (unsigned)GB) {
        // ---- scatter branch: single pass, 8 independent chains/thread ----
        const int chunk = blockIdx.x - GB;
        const int e0    = chunk * EPB;
        #pragma unroll 4
        for (int i = tid; i < EPB; i += 256) {
            int e = e0 + i;
            if (e < E) {
                int d = dst[e];
                int s = atomicAdd(&cur[d], 1);
                int2 rec = make_int2(src[e], __float_as_int(ev[e]));
                if (s < CAPN) {
                    tmp[(size_t)d * CAPN + s] = rec;
                } else {               // effectively impossible; kept correct
                    int o = atomicAdd(ovfc, 1);
                    if (o < E) ovf[o] = make_int4(rec.x, rec.y, d, 0);
                }
            }
        }
        return;
    }

    // ---- MFMA gemm branch ----
    const int gb   = blockIdx.x;
    const int lane = tid & 63;
    const int w    = tid >> 6;          // wave 0..3
    const int ln   = lane & 15;
    const int q    = lane >> 4;         // quad 0..3
    const int rowb = gb * TILE_ROWS + w * 16;
    const int arow = rowb + ln;

    // Stage W -> LDS bf16, transposed WT[n][k]; 16B slot XOR-swizzled by n&7.
    for (int idx = tid; idx < FIN * FOUT; idx += 256) {
        int k = idx >> 6;          // 0..127   (idx = k*FOUT + n)
        int n = idx & 63;          // 0..63
        sh.wt[n * FIN + (k ^ ((n & 7) << 3))] = f32_to_bf16_rne(W[idx]);
    }
    __syncthreads();

    f32x4 acc[4];
    #pragma unroll
    for (int nt = 0; nt < 4; ++nt)
        #pragma unroll
        for (int r = 0; r < 4; ++r) acc[nt][r] = 0.f;

    const bool aok = (arow < N);
    const float* xrow = &x[(size_t)arow * FIN];

    #pragma unroll
    for (int kc = 0; kc < 4; ++kc) {
        float xs[8];
        #pragma unroll
        for (int j = 0; j < 8; ++j) xs[j] = 0.f;
        if (aok) {
            float4 x0 = *(const float4*)&xrow[kc * 32 + q * 8];
            float4 x1 = *(const float4*)&xrow[kc * 32 + q * 8 + 4];
            xs[0] = x0.x; xs[1] = x0.y; xs[2] = x0.z; xs[3] = x0.w;
            xs[4] = x1.x; xs[5] = x1.y; xs[6] = x1.z; xs[7] = x1.w;
        }
        bf16x8 a;
        #pragma unroll
        for (int j = 0; j < 8; ++j) a[j] = (short)f32_to_bf16_rne(xs[j]);

        const int k0 = kc * 32 + q * 8;
        #pragma unroll
        for (int nt = 0; nt < 4; ++nt) {
            bf16x8 b = *(const bf16x8*)
                &sh.wt[(nt * 16 + ln) * FIN + (k0 ^ ((ln & 7) << 3))];
            acc[nt] = __builtin_amdgcn_mfma_f32_16x16x32_bf16(a, b, acc[nt], 0, 0, 0);
        }
    }

    // epilogue: D[m=q*4+reg][n=ln]; scale by t[row]; store bf16
    #pragma unroll
    for (int reg = 0; reg < 4; ++reg) {
        int r = rowb + q * 4 + reg;
        if (r < N) {
            float tv = t[r];
            #pragma unroll
            for (int nt = 0; nt < 4; ++nt)
                support[(size_t)r * FOUT + nt * 16 + ln] =
                    f32_to_bf16_rne(acc[nt][reg] * tv);
        }
    }
}

// ---------------------------------------------------------------------------
// gather: no LDS sort. Block = 64 nodes; 16-lane group per node (4 feats
// per lane), 4 nodes per group sequentially. Per 4-record step: 4 uniform
// row reads (L1-broadcast) + 4 support-row uint2 gathers in flight; one
// coalesced float4 store per node. Adjacent groups handle adjacent nodes
// (node = node0 + nn*16 + grp) so wave-level stores are 1KB contiguous.
// Zero-degree nodes fall out naturally (bias row).
// ---------------------------------------------------------------------------
__global__ __launch_bounds__(256) void gather_kernel(
    const int* __restrict__ cur, const int2* __restrict__ tmp,
    const ushort* __restrict__ support, const float* __restrict__ bias,
    float* __restrict__ out, const int* __restrict__ ovfc,
    const int4* __restrict__ ovf, int E, int N)
{
    __shared__ int novs;
    const int tid   = threadIdx.x;
    const int grp   = tid >> 4;         // 0..15
    const int fl    = tid & 15;         // feature block (4 feats)
    const int node0 = blockIdx.x * 64;
    const float4 bv4 = *(const float4*)&bias[fl * 4];

    #pragma unroll 1
    for (int nn = 0; nn < 4; ++nn) {
        const int node = node0 + nn * 16 + grp;
        if (node >= N) continue;
        int deg = cur[node];
        int dmax = (deg < CAPN) ? deg : CAPN;
        const int2* row = &tmp[(size_t)node * CAPN];

        float a0 = 0.f, a1 = 0.f, a2 = 0.f, a3 = 0.f;
        int j = 0;
        for (; j + 4 <= dmax; j += 4) {
            int2 r0 = row[j], r1 = row[j + 1], r2 = row[j + 2], r3 = row[j + 3];
            uint2 u0 = *(const uint2*)&support[(size_t)r0.x * FOUT + fl * 4];
            uint2 u1 = *(const uint2*)&support[(size_t)r1.x * FOUT + fl * 4];
            uint2 u2 = *(const uint2*)&support[(size_t)r2.x * FOUT + fl * 4];
            uint2 u3 = *(const uint2*)&support[(size_t)r3.x * FOUT + fl * 4];
            float w0 = __int_as_float(r0.y), w1 = __int_as_float(r1.y);
            float w2 = __int_as_float(r2.y), w3 = __int_as_float(r3.y);
            a0 += bf16_to_f32((ushort)(u0.x & 0xFFFFu)) * w0;
            a1 += bf16_to_f32((ushort)(u0.x >> 16)) * w0;
            a2 += bf16_to_f32((ushort)(u0.y & 0xFFFFu)) * w0;
            a3 += bf16_to_f32((ushort)(u0.y >> 16)) * w0;
            a0 += bf16_to_f32((ushort)(u1.x & 0xFFFFu)) * w1;
            a1 += bf16_to_f32((ushort)(u1.x >> 16)) * w1;
            a2 += bf16_to_f32((ushort)(u1.y & 0xFFFFu)) * w1;
            a3 += bf16_to_f32((ushort)(u1.y >> 16)) * w1;
            a0 += bf16_to_f32((ushort)(u2.x & 0xFFFFu)) * w2;
            a1 += bf16_to_f32((ushort)(u2.x >> 16)) * w2;
            a2 += bf16_to_f32((ushort)(u2.y & 0xFFFFu)) * w2;
            a3 += bf16_to_f32((ushort)(u2.y >> 16)) * w2;
            a0 += bf16_to_f32((ushort)(u3.x & 0xFFFFu)) * w3;
            a1 += bf16_to_f32((ushort)(u3.x >> 16)) * w3;
            a2 += bf16_to_f32((ushort)(u3.y & 0xFFFFu)) * w3;
            a3 += bf16_to_f32((ushort)(u3.y >> 16)) * w3;
        }
        for (; j < dmax; ++j) {
            int2 r = row[j];
            uint2 u = *(const uint2*)&support[(size_t)r.x * FOUT + fl * 4];
            float wg = __int_as_float(r.y);
            a0 += bf16_to_f32((ushort)(u.x & 0xFFFFu)) * wg;
            a1 += bf16_to_f32((ushort)(u.x >> 16)) * wg;
            a2 += bf16_to_f32((ushort)(u.y & 0xFFFFu)) * wg;
            a3 += bf16_to_f32((ushort)(u.y >> 16)) * wg;
        }
        float4 o;
        o.x = a0 + bv4.x; o.y = a1 + bv4.y;
        o.z = a2 + bv4.z; o.w = a3 + bv4.w;
        *(float4*)&out[(size_t)node * FOUT + fl * 4] = o;
    }

    // overflow tail: never taken at this size; kept for correctness.
    __syncthreads();
    if (tid == 0) novs = *ovfc;
    __syncthreads();
    int nov = novs;
    if (nov > 0) {
        if (nov > E) nov = E;
        __threadfence();
        const int w    = tid >> 6;
        const int lane = tid & 63;
        for (int k = w; k < nov; k += 4) {
            int4 r = ovf[k];
            int node = r.z;
            if (node >= node0 && node < node0 + 64 && node < N) {
                float v = bf16_to_f32(support[(size_t)r.x * FOUT + lane]);
                atomicAdd(&out[(size_t)node * FOUT + lane],
                          v * __int_as_float(r.y));
            }
        }
    }
}

extern "C" void kernel_launch(void* const* d_in, const int* in_sizes, int n_in,
                              void* d_out, int out_size, void* d_ws, size_t ws_size,
                              hipStream_t stream) {
    const float* x    = (const float*)d_in[0];
    const float* t    = (const float*)d_in[1];
    const int*   src  = (const int*)d_in[2];
    const int*   dst  = (const int*)d_in[3];
    const float* ev   = (const float*)d_in[4];
    const float* W    = (const float*)d_in[5];
    const float* bias = (const float*)d_in[6];
    float* out = (float*)d_out;

    const int N = in_sizes[1];   // 50000
    const int E = in_sizes[2];   // 800000

    char*   ws      = (char*)d_ws;
    ushort* support = (ushort*)ws;
    int*    cur     = (int*)(ws + OFF_CUR);
    int*    ovfc    = (int*)(ws + OFF_OVFC);
    int2*   tmp     = (int2*)(ws + OFF_TMP);
    int4*   ovf     = (int4*)(ws + OFF_OVF);

    const int GB  = (N + TILE_ROWS - 1) / TILE_ROWS;        // 782
    const int SBP = (E + EPB - 1) / EPB;                    // 391
    const int GBL = (N + 63) / 64;                          // 782 gather blocks

    // zero per-node cursors + overflow count (200 KB, graph-capturable)
    hipMemsetAsync(ws + OFF_CUR, 0, OFF_TMP - OFF_CUR, stream);

    // 1) fused independent branches: MFMA gemm || direct per-node scatter
    gemm_scatter_kernel<<<GB + SBP, 256, 0, stream>>>(
        x, t, W, support, N, src, dst, ev, cur, tmp, ovfc, ovf, E, SBP, GB);

    // 2) per-node gather-reduce -> out (+bias)
    gather_kernel<<<GBL, 256, 0, stream>>>(
        cur, tmp, support, bias, out, ovfc, ovf, E, N);
}

// Round 7
// 132.469 us; speedup vs baseline: 1.1608x; 1.1506x over previous
//
#include <hip/hip_runtime.h>
#include <hip/hip_bf16.h>

#define FIN 128
#define FOUT 64
#define TILE_ROWS 64       // rows per gemm block = 4 waves x 16

#define EPB 2048           // edges per scatter chunk (391 blocks)
#define NPB 32             // nodes per bucket (d >> 5)
#define NBUK_MAX 1600
#define CAP 768            // records per bucket region (mean 512, +11 sigma)

// Workspace layout (bytes), ws >= 268 MB:
//   [0, 6,400,000)         support : N*64 bf16
//   OFF_CUR   +6,400       cur     : NBUK int (bucket fill counters)
//   OFF_OVFC  +64          ovfc    : 1 int (overflow count)
//   OFF_TMP   +9,830,400   tmp     : NBUK_MAX*CAP int2 regions {src|dloc<<16, ev}
//   OFF_OVF   +12,800,000  ovf     : E int4 {recx, recy, bucket, pad}
#define OFF_CUR   6400000
#define OFF_OVFC  6406400
#define OFF_TMP   6406464
#define OFF_OVF   16236864

typedef short bf16x8 __attribute__((ext_vector_type(8)));
typedef float f32x4  __attribute__((ext_vector_type(4)));

__device__ inline ushort f32_to_bf16_rne(float f) {
    unsigned u = __float_as_uint(f);
    u += 0x7FFFu + ((u >> 16) & 1u);
    return (ushort)(u >> 16);
}
__device__ inline float bf16_to_f32(ushort h) {
    return __uint_as_float((unsigned)h << 16);
}

// ---------------------------------------------------------------------------
// Fused, independent branches (no fences, no intra-kernel ordering):
//   blocks [0,GB):       MFMA gemm (W staged to LDS bf16, transposed+swizzled)
//   blocks [GB,GB+SBP):  scatter chunk -> fixed-CAP 32-node-bucket regions.
// Scatter: LDS hist of the chunk -> ONE returning global atomicAdd per
// present bucket (range reservation) -> place via LDS cursors. Runs within
// a bucket region are contiguous (write amp ~1.5x vs R6's 8x).
// rec = {src | (d&31)<<16, ev_bits}   (src < 65536: N = 50000 ok)
// ---------------------------------------------------------------------------
union __align__(16) K1Sh {
    ushort wt[FOUT * FIN];                            // 16 KB (gemm)
    struct { int h[NBUK_MAX]; int c[NBUK_MAX]; } sc;  // 12.8 KB (scatter)
};

__global__ __launch_bounds__(256) void gemm_scatter_kernel(
    const float* __restrict__ x, const float* __restrict__ t,
    const float* __restrict__ W, ushort* __restrict__ support, int N,
    const int* __restrict__ src, const int* __restrict__ dst,
    const float* __restrict__ ev, int* __restrict__ cur,
    int2* __restrict__ tmp, int* __restrict__ ovfc, int4* __restrict__ ovf,
    int E, int SBP, int NBUK, int GB)
{
    __shared__ K1Sh sh;
    const int tid = threadIdx.x;

    if (blockIdx.x >= (unsigned)GB) {
        // ---- scatter branch ----
        const int chunk = blockIdx.x - GB;
        const int e0    = chunk * EPB;

        for (int i = tid; i < NBUK; i += 256) sh.sc.h[i] = 0;
        __syncthreads();

        // pass 1: local bucket counts
        for (int i = tid; i < EPB; i += 256) {
            int e = e0 + i;
            if (e < E) atomicAdd(&sh.sc.h[dst[e] >> 5], 1);
        }
        __syncthreads();

        // pass 2: reserve contiguous slices of bucket regions
        for (int j = tid; j < NBUK; j += 256) {
            int hj = sh.sc.h[j];
            if (hj) sh.sc.c[j] = atomicAdd(&cur[j], hj);
        }
        __syncthreads();

        // pass 3: place (dst re-read is L2-hot)
        for (int i = tid; i < EPB; i += 256) {
            int e = e0 + i;
            if (e < E) {
                int d = dst[e];
                int j = d >> 5;
                int s = atomicAdd(&sh.sc.c[j], 1);
                int2 rec = make_int2(src[e] | ((d & (NPB - 1)) << 16),
                                     __float_as_int(ev[e]));
                if (s < CAP) {
                    tmp[(size_t)j * CAP + s] = rec;
                } else {                 // never at this size; kept correct
                    int o = atomicAdd(ovfc, 1);
                    if (o < E) ovf[o] = make_int4(rec.x, rec.y, j, 0);
                }
            }
        }
        return;
    }

    // ---- MFMA gemm branch ----
    const int gb   = blockIdx.x;
    const int lane = tid & 63;
    const int w    = tid >> 6;          // wave 0..3
    const int ln   = lane & 15;
    const int q    = lane >> 4;         // quad 0..3
    const int rowb = gb * TILE_ROWS + w * 16;
    const int arow = rowb + ln;

    // Stage W -> LDS bf16, transposed WT[n][k]; 16B slot XOR-swizzled by n&7.
    for (int idx = tid; idx < FIN * FOUT; idx += 256) {
        int k = idx >> 6;          // 0..127   (idx = k*FOUT + n)
        int n = idx & 63;          // 0..63
        sh.wt[n * FIN + (k ^ ((n & 7) << 3))] = f32_to_bf16_rne(W[idx]);
    }
    __syncthreads();

    f32x4 acc[4];
    #pragma unroll
    for (int nt = 0; nt < 4; ++nt)
        #pragma unroll
        for (int r = 0; r < 4; ++r) acc[nt][r] = 0.f;

    const bool aok = (arow < N);
    const float* xrow = &x[(size_t)arow * FIN];

    #pragma unroll
    for (int kc = 0; kc < 4; ++kc) {
        float xs[8];
        #pragma unroll
        for (int j = 0; j < 8; ++j) xs[j] = 0.f;
        if (aok) {
            float4 x0 = *(const float4*)&xrow[kc * 32 + q * 8];
            float4 x1 = *(const float4*)&xrow[kc * 32 + q * 8 + 4];
            xs[0] = x0.x; xs[1] = x0.y; xs[2] = x0.z; xs[3] = x0.w;
            xs[4] = x1.x; xs[5] = x1.y; xs[6] = x1.z; xs[7] = x1.w;
        }
        bf16x8 a;
        #pragma unroll
        for (int j = 0; j < 8; ++j) a[j] = (short)f32_to_bf16_rne(xs[j]);

        const int k0 = kc * 32 + q * 8;
        #pragma unroll
        for (int nt = 0; nt < 4; ++nt) {
            bf16x8 b = *(const bf16x8*)
                &sh.wt[(nt * 16 + ln) * FIN + (k0 ^ ((ln & 7) << 3))];
            acc[nt] = __builtin_amdgcn_mfma_f32_16x16x32_bf16(a, b, acc[nt], 0, 0, 0);
        }
    }

    // epilogue: D[m=q*4+reg][n=ln]; scale by t[row]; store bf16
    #pragma unroll
    for (int reg = 0; reg < 4; ++reg) {
        int r = rowb + q * 4 + reg;
        if (r < N) {
            float tv = t[r];
            #pragma unroll
            for (int nt = 0; nt < 4; ++nt)
                support[(size_t)r * FOUT + nt * 16 + ln] =
                    f32_to_bf16_rne(acc[nt][reg] * tv);
        }
    }
}

// ---------------------------------------------------------------------------
// bucket_gather: one block per 32-node bucket (1563 blocks, ~6/CU resident).
// Region read once into LDS; count -> wave-0 shfl scan -> reorder -> walk v2:
// wave w owns 8 nodes; 4 record groups x 16 feature-lanes; per step 4
// support-row uint2 gathers in flight per group (16/wave); cross-group
// shfl_xor reduce; one coalesced float4 store per node. Zero-count nodes
// fall out naturally (empty loop -> bias row). No float atomics normally.
// ---------------------------------------------------------------------------
__global__ __launch_bounds__(256) void bucket_gather_kernel(
    const int* __restrict__ curg, const int2* __restrict__ tmp,
    const ushort* __restrict__ support, const float* __restrict__ bias,
    float* __restrict__ out, const int* __restrict__ ovfc,
    const int4* __restrict__ ovf, int E, int N, int NBUK)
{
    __shared__ int2 raw[CAP];           // 6 KB
    __shared__ int2 sorted[CAP];        // 6 KB
    __shared__ int  cnt[NPB];
    __shared__ int  starts[NPB + 1];
    __shared__ int  cur[NPB];
    __shared__ int  novs;

    const int tid   = threadIdx.x;
    const int w     = tid >> 6;
    const int lane  = tid & 63;
    const int B     = blockIdx.x;
    const int node0 = B * NPB;

    const int base   = B * CAP;
    const int tot    = curg[B];
    const int placed = (tot < CAP) ? tot : CAP;

    if (tid < NPB) cnt[tid] = 0;
    __syncthreads();

    // single global read of the region: stage + count
    for (int i = tid; i < placed; i += 256) {
        int2 r = tmp[base + i];
        raw[i] = r;
        atomicAdd(&cnt[(r.x >> 16) & (NPB - 1)], 1);
    }
    __syncthreads();

    // wave-0 shfl scan over 32 counters
    if (tid < 64) {
        int v   = (tid < NPB) ? cnt[tid] : 0;
        int val = v;
        #pragma unroll
        for (int d = 1; d < NPB; d <<= 1) {
            int n = __shfl_up(val, d);
            if (tid >= d) val += n;
        }
        if (tid < NPB) {
            starts[tid] = val - v;
            cur[tid]    = val - v;
        }
        if (tid == 0) starts[NPB] = placed;
    }
    __syncthreads();

    // reorder LDS -> LDS
    for (int i = tid; i < placed; i += 256) {
        int2 r  = raw[i];
        int pos = atomicAdd(&cur[(r.x >> 16) & (NPB - 1)], 1);
        sorted[pos] = r;
    }
    __syncthreads();

    // ---- walk v2: wave w owns nodes [w*8, (w+1)*8) ----
    const int fl = lane & 15;           // feature block 0..15 (4 feats each)
    const int g  = lane >> 4;           // record group 0..3
    const float4 bv4 = *(const float4*)&bias[fl * 4];

    for (int nn = 0; nn < 8; ++nn) {
        const int nl = w * 8 + nn;      // node-local index 0..31
        const int rb = starts[nl];
        const int re = starts[nl + 1];

        float a0 = 0.f, a1 = 0.f, a2 = 0.f, a3 = 0.f;
        for (int i = rb + g; i < re; i += 4) {
            int2 r = sorted[i];                           // broadcast in group
            uint2 u = *(const uint2*)
                &support[(size_t)(r.x & 0xFFFF) * FOUT + fl * 4];
            float wg = __int_as_float(r.y);
            a0 += bf16_to_f32((ushort)(u.x & 0xFFFFu)) * wg;
            a1 += bf16_to_f32((ushort)(u.x >> 16)) * wg;
            a2 += bf16_to_f32((ushort)(u.y & 0xFFFFu)) * wg;
            a3 += bf16_to_f32((ushort)(u.y >> 16)) * wg;
        }
        // reduce across the 4 record groups (lanes fl, fl+16, fl+32, fl+48)
        #pragma unroll
        for (int d = 16; d < 64; d <<= 1) {
            a0 += __shfl_xor(a0, d);
            a1 += __shfl_xor(a1, d);
            a2 += __shfl_xor(a2, d);
            a3 += __shfl_xor(a3, d);
        }
        const int node = node0 + nl;
        if (g == 0 && node < N) {
            float4 o;
            o.x = a0 + bv4.x; o.y = a1 + bv4.y;
            o.z = a2 + bv4.z; o.w = a3 + bv4.w;
            *(float4*)&out[(size_t)node * FOUT + fl * 4] = o;
        }
    }

    // overflow tail: never taken at this size; kept for correctness.
    __syncthreads();
    if (tid == 0) novs = *ovfc;
    __syncthreads();
    int nov = novs;
    if (nov > 0) {
        if (nov > E) nov = E;
        __threadfence();
        for (int k = w; k < nov; k += 4) {
            int4 r = ovf[k];
            if (r.z == B) {
                int node = node0 + ((r.x >> 16) & (NPB - 1));
                if (node < N) {
                    float v = bf16_to_f32(
                        support[(size_t)(r.x & 0xFFFF) * FOUT + lane]);
                    atomicAdd(&out[(size_t)node * FOUT + lane],
                              v * __int_as_float(r.y));
                }
            }
        }
    }
}

extern "C" void kernel_launch(void* const* d_in, const int* in_sizes, int n_in,
                              void* d_out, int out_size, void* d_ws, size_t ws_size,
                              hipStream_t stream) {
    const float* x    = (const float*)d_in[0];
    const float* t    = (const float*)d_in[1];
    const int*   src  = (const int*)d_in[2];
    const int*   dst  = (const int*)d_in[3];
    const float* ev   = (const float*)d_in[4];
    const float* W    = (const float*)d_in[5];
    const float* bias = (const float*)d_in[6];
    float* out = (float*)d_out;

    const int N = in_sizes[1];   // 50000
    const int E = in_sizes[2];   // 800000

    char*   ws      = (char*)d_ws;
    ushort* support = (ushort*)ws;
    int*    cur     = (int*)(ws + OFF_CUR);
    int*    ovfc    = (int*)(ws + OFF_OVFC);
    int2*   tmp     = (int2*)(ws + OFF_TMP);
    int4*   ovf     = (int4*)(ws + OFF_OVF);

    const int GB   = (N + TILE_ROWS - 1) / TILE_ROWS;       // 782
    const int SBP  = (E + EPB - 1) / EPB;                   // 391
    const int NBUK = (N + NPB - 1) / NPB;                   // 1563

    // zero bucket cursors + overflow count (6.5 KB, graph-capturable)
    hipMemsetAsync(ws + OFF_CUR, 0, OFF_TMP - OFF_CUR, stream);

    // 1) fused independent branches: MFMA gemm || bucket-region scatter
    gemm_scatter_kernel<<<GB + SBP, 256, 0, stream>>>(
        x, t, W, support, N, src, dst, ev, cur, tmp, ovfc, ovf,
        E, SBP, NBUK, GB);

    // 2) per-bucket LDS sort + 4-wide record walk -> out (+bias)
    bucket_gather_kernel<<<NBUK, 256, 0, stream>>>(
        cur, tmp, support, bias, out, ovfc, ovf, E, N, NBUK);
}